// Round 1
// baseline (205.905 us; speedup 1.0000x reference)
//
#include <hip/hip_runtime.h>
#include <cstdint>

typedef __attribute__((ext_vector_type(8))) short short8;
typedef __attribute__((ext_vector_type(4))) float floatx4;

#define TWO_PI 6.283185307179586f

__device__ __forceinline__ unsigned short f2bf(float f) {
  union { float f; uint32_t u; } c; c.f = f;
  uint32_t u = c.u;
  u += 0x7FFFu + ((u >> 16) & 1u);   // RNE
  return (unsigned short)(u >> 16);
}
__device__ __forceinline__ uint32_t packbf(float re, float im) {
  return (uint32_t)f2bf(re) | ((uint32_t)f2bf(im) << 16);
}

// ---------------------------------------------------------------------------
// Four-step DFT convolution, N = 65536 = 256 x 256, t = c + 256 r, k = k1 + 256 k2.
// z_s = x[2s] + i x[2s+1].  All 256-pt DFT stages are real bf16 MFMA GEMMs via
// the 2x2 rotation embedding.
// ---------------------------------------------------------------------------

// Merged prep: blocks [0,3072) build A1..A4; [3072,4096) transpose/pack x->Zp;
// [4096,4352) compute Gw[k1][c]; [4352,4608) the mid twiddle table Tw[k1][c].
__global__ __launch_bounds__(256) void prep_all(
    const float* __restrict__ x, const float* __restrict__ filt,
    unsigned short* __restrict__ A1, unsigned short* __restrict__ A2,
    unsigned short* __restrict__ A3, unsigned short* __restrict__ A4,
    uint32_t* __restrict__ Zp, float2* __restrict__ Gw,
    float2* __restrict__ Tw) {
  const int bid = blockIdx.x;
  const int tid = threadIdx.x;
  const float w256 = TWO_PI / 256.0f;
  if (bid < 3072) {
    int idx = bid * 256 + tid;
    if (idx < 131072) {                       // A1 [512x256], E-(k1 r/256)
      int col = idx & 255, row = idx >> 8;
      int k1 = row >> 1, d = row & 1, r = col >> 1, e = col & 1;
      float th = (float)((k1 * r) & 255) * w256;
      float sn, cs; __sincosf(th, &sn, &cs);
      A1[idx] = f2bf(d == 0 ? (e == 0 ? cs : sn) : (e == 0 ? -sn : cs));
    } else if (idx < 393216) {                // A2 [512x512], E-(k2 c/256)
      int j = idx - 131072;
      int col = j & 511, row = j >> 9;
      int k2 = row >> 1, d = row & 1, cc = col >> 1, e = col & 1;
      float th = (float)((k2 * cc) & 255) * w256;
      float sn, cs; __sincosf(th, &sn, &cs);
      A2[j] = f2bf(d == 0 ? (e == 0 ? cs : sn) : (e == 0 ? -sn : cs));
    } else if (idx < 655360) {                // A3 [512x512], rows 2c+d, E+(k2 c/256)
      int j = idx - 393216;
      int col = j & 511, row = j >> 9;
      int cc = row >> 1, d = row & 1, k2 = col >> 1, e = col & 1;
      float th = (float)((k2 * cc) & 255) * w256;
      float sn, cs; __sincosf(th, &sn, &cs);
      A3[j] = f2bf(d == 0 ? (e == 0 ? cs : -sn) : (e == 0 ? sn : cs));
    } else {                                  // A4 [256x512], rows 2r+d, E+(k1 r/256)
      int j = idx - 655360;
      int col = j & 511, row = j >> 9;
      int r = row >> 1, d = row & 1, k1 = col >> 1, e = col & 1;
      float th = (float)((k1 * r) & 255) * w256;
      float sn, cs; __sincosf(th, &sn, &cs);
      A4[j] = f2bf(d == 0 ? (e == 0 ? cs : -sn) : (e == 0 ? sn : cs));
    }
  } else if (bid < 4096) {                    // Zp[(s*256+c)][r] packed bf16 pair
    int b2 = bid - 3072;                      // 1024 blocks: (s, r-chunk of 16)
    int s = b2 >> 3, rq = b2 & 7;
    const float* x0 = x + (size_t)(2 * s) * 32768;
    const float* x1 = x0 + 32768;
    uint32_t v[16];
    #pragma unroll
    for (int rr = 0; rr < 16; ++rr) {
      int t = tid + 256 * (rq * 16 + rr);
      v[rr] = (uint32_t)f2bf(x0[t]) | ((uint32_t)f2bf(x1[t]) << 16);
    }
    uint32_t* dst = Zp + (size_t)(s * 256 + tid) * 128 + rq * 16;
    #pragma unroll
    for (int j = 0; j < 16; j += 4)
      *(uint4*)(dst + j) = make_uint4(v[j], v[j + 1], v[j + 2], v[j + 3]);
  } else if (bid < 4352) {                    // Gw[k1][c], fp32
    int k1 = bid - 4096, c = tid;
    float ar = 0.f, ai = 0.f;
    for (int r = 0; r < 128; ++r) {
      float v = filt[c + 256 * r];
      float th = (float)((k1 * r) & 255) * w256;
      float sn, cs; __sincosf(th, &sn, &cs);
      ar += v * cs; ai -= v * sn;
    }
    float th = (float)((k1 * c) & 65535) * (TWO_PI / 65536.0f);
    float sn, cs; __sincosf(th, &sn, &cs);
    Gw[(k1 << 8) + c] = make_float2(ar * cs + ai * sn, ai * cs - ar * sn);
  } else {                                    // Tw[k1][c] = (cos, sin) of k1*c/65536
    int k1 = bid - 4352, c = tid;
    float th = (float)((k1 * c) & 65535) * (TWO_PI / 65536.0f);
    float sn, cs; __sincosf(th, &sn, &cs);
    Tw[(k1 << 8) + c] = make_float2(cs, sn);
  }
}

// WtT[k2][k1] = sum_c Gw[k1][c] E-(k2 c/256)   (fp32, TRANSPOSED for coalesced epilogue)
__global__ __launch_bounds__(256) void prep_wb(const float2* __restrict__ Gw,
                                               float2* __restrict__ WtT) {
  int k1 = blockIdx.x, k2 = threadIdx.x;
  float ar = 0.f, ai = 0.f;
  for (int c = 0; c < 256; ++c) {
    float2 g = Gw[(k1 << 8) + c];             // wave-uniform broadcast
    float th = (float)((k2 * c) & 255) * (TWO_PI / 256.0f);
    float sn, cs; __sincosf(th, &sn, &cs);
    ar += g.x * cs + g.y * sn;
    ai += g.y * cs - g.x * sn;
  }
  WtT[(k2 << 8) + k1] = make_float2(ar, ai);
}

// One DFT stage = real bf16 GEMM C[m][n] = sum_k A[m][k] B[n][k] + mode epilogue.
// K=32 chunks, 4 LDS buffers, 3-deep prefetch, counted vmcnt (never drain mid-loop).
// LDS pair-line layout: pair-line P (2 rows, 128 B) slot s in [0,8) holds
// g = s ^ (P&7) -> row 2P+(g&1), k-chunk (g>>1)*8 shorts.  global_load_lds dest
// stays linear (base+lane*16); the swizzle is applied on the global source
// address (write side) and on the ds_read address (read side).  Read pattern is
// a bijection lane->slot per 1 KB row-block: conflict-free.
// MODE 1: *Tw(E-) -> G2[(s,k1)][c].   MODE 2: *WtT -> P[(s,k1)][k2] (LDS transpose).
// MODE 3: *Tw(E+) -> H2[(s,c)][k1].   MODE 4: write y (scale 1/65536).
template <int MODE, int NCHUNK>
__global__ __launch_bounds__(256, 2) void dft_stage(
    const unsigned short* __restrict__ Af,
    const unsigned short* __restrict__ Bd,
    uint32_t* __restrict__ outp,
    float* __restrict__ yout,
    const float2* __restrict__ tab) {
  __shared__ unsigned short Sm[32768];        // 4 A-bufs (8 KB) + 4 B-bufs (8 KB)
  constexpr int KP = NCHUNK * 32;

  const int mt = blockIdx.x >> 8;
  const int nt = blockIdx.x & 255;
  const int m0 = mt * 128, n0 = nt * 128;

  const int tid = threadIdx.x;
  const int w = tid >> 6, lane = tid & 63;
  const int qlo = lane & 15, qhi = lane >> 4;
  const int wr = w >> 1, wc = w & 1;
  // staging lane constants (global-side pre-swizzle)
  const int lj = lane >> 3;                   // pair-line sub-index 0..7
  const int g = (lane & 7) ^ lj;              // slot content selector
  const int hsel = g & 1, qk8 = (g >> 1) << 3;

  floatx4 acc[4][4];
  #pragma unroll
  for (int i = 0; i < 4; ++i)
    #pragma unroll
    for (int j = 0; j < 4; ++j) acc[i][j] = (floatx4){0.f, 0.f, 0.f, 0.f};

  auto issue = [&](int t) {
    const int buf = t & 3;
    const int k0 = t * 32;
    unsigned short* Asb = Sm + buf * 4096;
    unsigned short* Bsb = Sm + 16384 + buf * 4096;
    #pragma unroll
    for (int q = 0; q < 2; ++q) {
      const int PL = w * 16 + q * 8;          // wave-uniform pair-line base
      const int R = 2 * (PL + lj) + hsel;     // per-lane global row
      const unsigned short* gA = Af + (size_t)(m0 + R) * KP + k0 + qk8;
      const unsigned short* gB = Bd + (size_t)(n0 + R) * KP + k0 + qk8;
      __builtin_amdgcn_global_load_lds(
          (const __attribute__((address_space(1))) uint32_t*)gA,
          (__attribute__((address_space(3))) uint32_t*)&Asb[PL * 64], 16, 0, 0);
      __builtin_amdgcn_global_load_lds(
          (const __attribute__((address_space(1))) uint32_t*)gB,
          (__attribute__((address_space(3))) uint32_t*)&Bsb[PL * 64], 16, 0, 0);
    }
  };

  issue(0); issue(1); issue(2);               // 3-deep prologue (12 loads/wave)
  #pragma unroll
  for (int t = 0; t < NCHUNK; ++t) {
    // wait for chunk t's 4 loads; keep up to 2 future chunks (8 loads) in flight
    const int rem = NCHUNK - 1 - t;
    if (rem >= 2)      asm volatile("s_waitcnt vmcnt(8)" ::: "memory");
    else if (rem == 1) asm volatile("s_waitcnt vmcnt(4)" ::: "memory");
    else               asm volatile("s_waitcnt vmcnt(0)" ::: "memory");
    __builtin_amdgcn_s_barrier();             // all waves' chunk-t data visible
    if (t + 3 < NCHUNK) issue(t + 3);         // buf (t-1)&3: consumed pre-barrier
    __builtin_amdgcn_sched_barrier(0);
    const unsigned short* Ab = Sm + (t & 3) * 4096;
    const unsigned short* Bb = Sm + 16384 + (t & 3) * 4096;
    short8 a[4], bb[4];
    #pragma unroll
    for (int im = 0; im < 4; ++im) {
      const int R = wr * 64 + im * 16 + qlo;
      const int P = R >> 1;
      a[im] = *(const short8*)&Ab[(P << 6) + ((((qhi << 1) | (R & 1)) ^ (P & 7)) << 3)];
    }
    #pragma unroll
    for (int in = 0; in < 4; ++in) {
      const int R = wc * 64 + in * 16 + qlo;
      const int P = R >> 1;
      bb[in] = *(const short8*)&Bb[(P << 6) + ((((qhi << 1) | (R & 1)) ^ (P & 7)) << 3)];
    }
    __builtin_amdgcn_s_setprio(1);
    #pragma unroll
    for (int im = 0; im < 4; ++im)
      #pragma unroll
      for (int in = 0; in < 4; ++in)
        acc[im][in] = __builtin_amdgcn_mfma_f32_16x16x32_bf16(a[im], bb[in], acc[im][in], 0, 0, 0);
    __builtin_amdgcn_s_setprio(0);
  }

  const int s_idx = n0 >> 8;                  // block-constant (128 | 256)
  const int cl0 = n0 & 255;

  if (MODE == 2) {
    __syncthreads();                          // staging buffers now dead -> reuse
    uint32_t* Tr = (uint32_t*)Sm;             // [128 n][68 pad] u32
    #pragma unroll
    for (int im = 0; im < 4; ++im) {
      const int mloc = wr * 32 + im * 8 + qhi * 2;
      #pragma unroll
      for (int in = 0; in < 4; ++in) {
        const int nloc = wc * 64 + in * 16 + qlo;
        #pragma unroll
        for (int pp = 0; pp < 2; ++pp) {
          const int mC = (m0 >> 1) + mloc + pp;         // global k2
          float re = acc[im][in][2 * pp], iv = acc[im][in][2 * pp + 1];
          float2 wv = tab[(mC << 8) + cl0 + nloc];      // WtT, coalesced (lanes->k1)
          float r2 = re * wv.x - iv * wv.y, i2 = re * wv.y + iv * wv.x;
          Tr[nloc * 68 + mloc + pp] = packbf(r2, i2);
        }
      }
    }
    __syncthreads();
    const int ln = tid >> 1, half = tid & 1;
    uint32_t* dst = outp + (size_t)((s_idx << 8) + cl0 + ln) * 256 + (m0 >> 1) + half * 32;
    const uint32_t* srcp = Tr + ln * 68 + half * 32;
    #pragma unroll
    for (int j = 0; j < 32; j += 4)
      *(uint4*)(dst + j) = *(const uint4*)(srcp + j);
    return;
  }

  #pragma unroll
  for (int im = 0; im < 4; ++im) {
    const int mloc = wr * 32 + im * 8 + qhi * 2;
    #pragma unroll
    for (int in = 0; in < 4; ++in) {
      const int nloc = wc * 64 + in * 16 + qlo;
      const int cloc = cl0 + nloc;
      #pragma unroll
      for (int pp = 0; pp < 2; ++pp) {
        const int mC = (m0 >> 1) + mloc + pp;
        float re = acc[im][in][2 * pp], iv = acc[im][in][2 * pp + 1];
        if (MODE == 1) {
          float2 tw = tab[(mC << 8) + cloc];            // E- table (coalesced)
          float r2 = re * tw.x + iv * tw.y, i2 = iv * tw.x - re * tw.y;
          outp[(size_t)((s_idx << 8) + mC) * 256 + cloc] = packbf(r2, i2);
        } else if (MODE == 3) {
          float2 tw = tab[(mC << 8) + cloc];            // E+ table
          float r2 = re * tw.x - iv * tw.y, i2 = iv * tw.x + re * tw.y;
          outp[(size_t)((s_idx << 8) + mC) * 256 + cloc] = packbf(r2, i2);
        } else {                                        // MODE 4: final y
          const float sc = 1.0f / 65536.0f;
          float* y0 = yout + ((size_t)s_idx << 16) + (mC << 8) + cloc;
          y0[0] = re * sc;        // y[2s][c+256r]
          y0[32768] = iv * sc;    // y[2s+1][c+256r]
        }
      }
    }
  }
}

extern "C" void kernel_launch(void* const* d_in, const int* in_sizes, int n_in,
                              void* d_out, int out_size, void* d_ws, size_t ws_size,
                              hipStream_t stream) {
  const float* x = (const float*)d_in[0];     // [256][32768] fp32
  const float* filt = (const float*)d_in[1];  // [1][32768] fp32
  float* Y = (float*)d_out;                   // [256][32768] fp32

  char* ws = (char*)d_ws;
  unsigned short* A1 = (unsigned short*)(ws + 0);              // 256 KB
  unsigned short* A2 = (unsigned short*)(ws + 0x40000);        // 512 KB
  unsigned short* A3 = (unsigned short*)(ws + 0xC0000);        // 512 KB
  unsigned short* A4 = (unsigned short*)(ws + 0x140000);       // 256 KB
  float2* Gw  = (float2*)(ws + 0x180000);                      // 512 KB
  float2* WtT = (float2*)(ws + 0x200000);                      // 512 KB
  float2* Tw  = (float2*)(ws + 0x280000);                      // 512 KB
  unsigned short* Zp = (unsigned short*)(ws + (3u << 20));     // 16 MB  [3,19)
  unsigned short* G2 = (unsigned short*)(ws + 19922944u);      // 32 MB  [19,51)
  unsigned short* P  = (unsigned short*)(ws + 53477376u);      // 32 MB  [51,83)
  unsigned short* H2 = (unsigned short*)(ws + (3u << 20));     // 32 MB, reuses Zp+G2 (dead)

  hipLaunchKernelGGL(prep_all, dim3(4608), dim3(256), 0, stream,
                     x, filt, A1, A2, A3, A4, (uint32_t*)Zp, Gw, Tw);
  hipLaunchKernelGGL(prep_wb, dim3(256), dim3(256), 0, stream, Gw, WtT);

  hipLaunchKernelGGL((dft_stage<1, 8>), dim3(1024), dim3(256), 0, stream,
                     A1, Zp, (uint32_t*)G2, (float*)nullptr, Tw);
  hipLaunchKernelGGL((dft_stage<2, 16>), dim3(1024), dim3(256), 0, stream,
                     A2, G2, (uint32_t*)P, (float*)nullptr, WtT);
  hipLaunchKernelGGL((dft_stage<3, 16>), dim3(1024), dim3(256), 0, stream,
                     A3, P, (uint32_t*)H2, (float*)nullptr, Tw);
  hipLaunchKernelGGL((dft_stage<4, 16>), dim3(512), dim3(256), 0, stream,
                     A4, H2, (uint32_t*)nullptr, Y, Tw);
}

// Round 2
// 199.841 us; speedup vs baseline: 1.0303x; 1.0303x over previous
//
#include <hip/hip_runtime.h>
#include <cstdint>

typedef __attribute__((ext_vector_type(8))) short short8;
typedef __attribute__((ext_vector_type(4))) float floatx4;

#define TWO_PI 6.283185307179586f

__device__ __forceinline__ unsigned short f2bf(float f) {
  union { float f; uint32_t u; } c; c.f = f;
  uint32_t u = c.u;
  u += 0x7FFFu + ((u >> 16) & 1u);   // RNE
  return (unsigned short)(u >> 16);
}
__device__ __forceinline__ uint32_t packbf(float re, float im) {
  return (uint32_t)f2bf(re) | ((uint32_t)f2bf(im) << 16);
}

// ---------------------------------------------------------------------------
// Four-step DFT convolution, N = 65536 = 256 x 256, t = c + 256 r, k = k1 + 256 k2.
// z_s = x[2s] + i x[2s+1].  All 256-pt DFT stages are real bf16 MFMA GEMMs via
// the 2x2 rotation embedding.
// ---------------------------------------------------------------------------

// Merged prep: blocks [0,3072) build A1..A4; [3072,4096) transpose/pack x->Zp;
// [4096,4352) compute Gw[k1][c]; [4352,4608) the mid twiddle table Tw[k1][c].
__global__ __launch_bounds__(256) void prep_all(
    const float* __restrict__ x, const float* __restrict__ filt,
    unsigned short* __restrict__ A1, unsigned short* __restrict__ A2,
    unsigned short* __restrict__ A3, unsigned short* __restrict__ A4,
    uint32_t* __restrict__ Zp, float2* __restrict__ Gw,
    float2* __restrict__ Tw) {
  const int bid = blockIdx.x;
  const int tid = threadIdx.x;
  const float w256 = TWO_PI / 256.0f;
  if (bid < 3072) {
    int idx = bid * 256 + tid;
    if (idx < 131072) {                       // A1 [512x256], E-(k1 r/256)
      int col = idx & 255, row = idx >> 8;
      int k1 = row >> 1, d = row & 1, r = col >> 1, e = col & 1;
      float th = (float)((k1 * r) & 255) * w256;
      float sn, cs; __sincosf(th, &sn, &cs);
      A1[idx] = f2bf(d == 0 ? (e == 0 ? cs : sn) : (e == 0 ? -sn : cs));
    } else if (idx < 393216) {                // A2 [512x512], E-(k2 c/256)
      int j = idx - 131072;
      int col = j & 511, row = j >> 9;
      int k2 = row >> 1, d = row & 1, cc = col >> 1, e = col & 1;
      float th = (float)((k2 * cc) & 255) * w256;
      float sn, cs; __sincosf(th, &sn, &cs);
      A2[j] = f2bf(d == 0 ? (e == 0 ? cs : sn) : (e == 0 ? -sn : cs));
    } else if (idx < 655360) {                // A3 [512x512], rows 2c+d, E+(k2 c/256)
      int j = idx - 393216;
      int col = j & 511, row = j >> 9;
      int cc = row >> 1, d = row & 1, k2 = col >> 1, e = col & 1;
      float th = (float)((k2 * cc) & 255) * w256;
      float sn, cs; __sincosf(th, &sn, &cs);
      A3[j] = f2bf(d == 0 ? (e == 0 ? cs : -sn) : (e == 0 ? sn : cs));
    } else {                                  // A4 [256x512], rows 2r+d, E+(k1 r/256)
      int j = idx - 655360;
      int col = j & 511, row = j >> 9;
      int r = row >> 1, d = row & 1, k1 = col >> 1, e = col & 1;
      float th = (float)((k1 * r) & 255) * w256;
      float sn, cs; __sincosf(th, &sn, &cs);
      A4[j] = f2bf(d == 0 ? (e == 0 ? cs : -sn) : (e == 0 ? sn : cs));
    }
  } else if (bid < 4096) {                    // Zp[(s*256+c)][r] packed bf16 pair
    int b2 = bid - 3072;                      // 1024 blocks: (s, r-chunk of 16)
    int s = b2 >> 3, rq = b2 & 7;
    const float* x0 = x + (size_t)(2 * s) * 32768;
    const float* x1 = x0 + 32768;
    uint32_t v[16];
    #pragma unroll
    for (int rr = 0; rr < 16; ++rr) {
      int t = tid + 256 * (rq * 16 + rr);
      v[rr] = (uint32_t)f2bf(x0[t]) | ((uint32_t)f2bf(x1[t]) << 16);
    }
    uint32_t* dst = Zp + (size_t)(s * 256 + tid) * 128 + rq * 16;
    #pragma unroll
    for (int j = 0; j < 16; j += 4)
      *(uint4*)(dst + j) = make_uint4(v[j], v[j + 1], v[j + 2], v[j + 3]);
  } else if (bid < 4352) {                    // Gw[k1][c], fp32
    int k1 = bid - 4096, c = tid;
    float ar = 0.f, ai = 0.f;
    for (int r = 0; r < 128; ++r) {
      float v = filt[c + 256 * r];
      float th = (float)((k1 * r) & 255) * w256;
      float sn, cs; __sincosf(th, &sn, &cs);
      ar += v * cs; ai -= v * sn;
    }
    float th = (float)((k1 * c) & 65535) * (TWO_PI / 65536.0f);
    float sn, cs; __sincosf(th, &sn, &cs);
    Gw[(k1 << 8) + c] = make_float2(ar * cs + ai * sn, ai * cs - ar * sn);
  } else {                                    // Tw[k1][c] = (cos, sin) of k1*c/65536
    int k1 = bid - 4352, c = tid;
    float th = (float)((k1 * c) & 65535) * (TWO_PI / 65536.0f);
    float sn, cs; __sincosf(th, &sn, &cs);
    Tw[(k1 << 8) + c] = make_float2(cs, sn);
  }
}

// WtT[k2][k1] = sum_c Gw[k1][c] E-(k2 c/256)   (fp32, TRANSPOSED for coalesced epilogue)
__global__ __launch_bounds__(256) void prep_wb(const float2* __restrict__ Gw,
                                               float2* __restrict__ WtT) {
  int k1 = blockIdx.x, k2 = threadIdx.x;
  float ar = 0.f, ai = 0.f;
  for (int c = 0; c < 256; ++c) {
    float2 g = Gw[(k1 << 8) + c];             // wave-uniform broadcast
    float th = (float)((k2 * c) & 255) * (TWO_PI / 256.0f);
    float sn, cs; __sincosf(th, &sn, &cs);
    ar += g.x * cs + g.y * sn;
    ai += g.y * cs - g.x * sn;
  }
  WtT[(k2 << 8) + k1] = make_float2(ar, ai);
}

// One DFT stage = real bf16 GEMM C[m][n] = sum_k A[m][k] B[n][k] + mode epilogue.
// BK=32 chunks, 2 LDS buffers (32 KB total -> 4 blocks/CU co-resident = 16
// waves/CU; inter-block phase offset is the latency-hiding mechanism, m114).
// LDS tile [128 rows][32 shorts]; row = 64 B = 4 slots of 16 B.
// Swizzle: content of (row R, slot s) = k-group g = s ^ ((R>>1)&3).
//   Read:  lane(qlo,qhi) row R=base+qlo, slot = qhi ^ ((qlo>>1)&3) -> within any
//          consecutive-8-lane phase (row-parity, slot) is a bijection -> banks
//          0..31 covered exactly, conflict-free.
//   Write: global_load_lds dest stays linear (base + lane*16); the same
//          permutation is applied to the per-lane GLOBAL source address:
//          g = (lane&3) ^ ((lane>>3)&3)   (both-sides-or-neither, rule #21).
// MODE 1: *Tw(E-) -> G2[(s,k1)][c].   MODE 2: *WtT -> P[(s,k1)][k2] (LDS transpose).
// MODE 3: *Tw(E+) -> H2[(s,c)][k1].   MODE 4: write y (scale 1/65536).
template <int MODE, int NCHUNK>
__global__ __launch_bounds__(256, 4) void dft_stage(
    const unsigned short* __restrict__ Af,
    const unsigned short* __restrict__ Bd,
    uint32_t* __restrict__ outp,
    float* __restrict__ yout,
    const float2* __restrict__ tab) {
  __shared__ unsigned short Sm[16384];        // A: 2x4096, B: 2x4096 shorts (32 KB)
  constexpr int KP = NCHUNK * 32;

  const int mt = blockIdx.x >> 8;
  const int nt = blockIdx.x & 255;
  const int m0 = mt * 128, n0 = nt * 128;

  const int tid = threadIdx.x;
  const int w = tid >> 6, lane = tid & 63;
  const int qlo = lane & 15, qhi = lane >> 4;
  const int wr = w >> 1, wc = w & 1;
  // staging lane constants (global-side pre-swizzle)
  const int rsub = lane >> 2;                       // row within 16-row group
  const int koff = ((lane & 3) ^ ((lane >> 3) & 3)) << 3;  // swizzled k-offset

  floatx4 acc[4][4];
  #pragma unroll
  for (int i = 0; i < 4; ++i)
    #pragma unroll
    for (int j = 0; j < 4; ++j) acc[i][j] = (floatx4){0.f, 0.f, 0.f, 0.f};

  auto issue = [&](int t) {
    const int buf = t & 1;
    const int k0 = t * 32;
    unsigned short* Asb = Sm + buf * 4096;
    unsigned short* Bsb = Sm + 8192 + buf * 4096;
    #pragma unroll
    for (int q = 0; q < 2; ++q) {
      const int rowbase = w * 32 + q * 16;          // wave-uniform
      const int R = rowbase + rsub;                 // per-lane global row
      const unsigned short* gA = Af + (size_t)(m0 + R) * KP + k0 + koff;
      const unsigned short* gB = Bd + (size_t)(n0 + R) * KP + k0 + koff;
      __builtin_amdgcn_global_load_lds(
          (const __attribute__((address_space(1))) uint32_t*)gA,
          (__attribute__((address_space(3))) uint32_t*)&Asb[rowbase * 32], 16, 0, 0);
      __builtin_amdgcn_global_load_lds(
          (const __attribute__((address_space(1))) uint32_t*)gB,
          (__attribute__((address_space(3))) uint32_t*)&Bsb[rowbase * 32], 16, 0, 0);
    }
  };

  issue(0);
  #pragma unroll
  for (int t = 0; t < NCHUNK; ++t) {
    asm volatile("s_waitcnt vmcnt(0)" ::: "memory");  // chunk t's 4 loads done
    __builtin_amdgcn_s_barrier();                     // tile visible to all waves
    if (t + 1 < NCHUNK) issue(t + 1);                 // buf (t+1)&1: consumed at t-1
    __builtin_amdgcn_sched_barrier(0);
    const unsigned short* Ab = Sm + (t & 1) * 4096;
    const unsigned short* Bb = Sm + 8192 + (t & 1) * 4096;
    short8 a[4], bb[4];
    #pragma unroll
    for (int im = 0; im < 4; ++im) {
      const int R = wr * 64 + im * 16 + qlo;
      const int slot = qhi ^ ((R >> 1) & 3);
      a[im] = *(const short8*)&Ab[R * 32 + slot * 8];
    }
    #pragma unroll
    for (int in = 0; in < 4; ++in) {
      const int R = wc * 64 + in * 16 + qlo;
      const int slot = qhi ^ ((R >> 1) & 3);
      bb[in] = *(const short8*)&Bb[R * 32 + slot * 8];
    }
    __builtin_amdgcn_s_setprio(1);
    #pragma unroll
    for (int im = 0; im < 4; ++im)
      #pragma unroll
      for (int in = 0; in < 4; ++in)
        acc[im][in] = __builtin_amdgcn_mfma_f32_16x16x32_bf16(a[im], bb[in], acc[im][in], 0, 0, 0);
    __builtin_amdgcn_s_setprio(0);
  }

  const int s_idx = n0 >> 8;                  // block-constant (128 | 256)
  const int cl0 = n0 & 255;

  if (MODE == 2) {
    // Transpose via LDS in two 64-row half-passes (fits 32 KB: [64][68] u32).
    uint32_t* Tr = (uint32_t*)Sm;
    #pragma unroll
    for (int h = 0; h < 2; ++h) {
      __syncthreads();                        // staging (or prev pass) dead
      if (wc == h) {
        #pragma unroll
        for (int im = 0; im < 4; ++im) {
          const int mloc = wr * 32 + im * 8 + qhi * 2;
          #pragma unroll
          for (int in = 0; in < 4; ++in) {
            const int nl = in * 16 + qlo;               // 0..63 within half
            #pragma unroll
            for (int pp = 0; pp < 2; ++pp) {
              const int mC = (m0 >> 1) + mloc + pp;     // global k2
              float re = acc[im][in][2 * pp], iv = acc[im][in][2 * pp + 1];
              float2 wv = tab[(mC << 8) + cl0 + h * 64 + nl]; // WtT, coalesced
              float r2 = re * wv.x - iv * wv.y, i2 = re * wv.y + iv * wv.x;
              Tr[nl * 68 + mloc + pp] = packbf(r2, i2);
            }
          }
        }
      }
      __syncthreads();
      const int row = tid >> 2, qq = tid & 3;
      uint32_t* dst = outp + (size_t)((s_idx << 8) + cl0 + h * 64 + row) * 256 +
                      (m0 >> 1) + qq * 16;
      const uint32_t* srcp = Tr + row * 68 + qq * 16;
      #pragma unroll
      for (int j = 0; j < 16; j += 4)
        *(uint4*)(dst + j) = *(const uint4*)(srcp + j);
    }
    return;
  }

  #pragma unroll
  for (int im = 0; im < 4; ++im) {
    const int mloc = wr * 32 + im * 8 + qhi * 2;
    #pragma unroll
    for (int in = 0; in < 4; ++in) {
      const int nloc = wc * 64 + in * 16 + qlo;
      const int cloc = cl0 + nloc;
      #pragma unroll
      for (int pp = 0; pp < 2; ++pp) {
        const int mC = (m0 >> 1) + mloc + pp;
        float re = acc[im][in][2 * pp], iv = acc[im][in][2 * pp + 1];
        if (MODE == 1) {
          float2 tw = tab[(mC << 8) + cloc];            // E- table (coalesced)
          float r2 = re * tw.x + iv * tw.y, i2 = iv * tw.x - re * tw.y;
          outp[(size_t)((s_idx << 8) + mC) * 256 + cloc] = packbf(r2, i2);
        } else if (MODE == 3) {
          float2 tw = tab[(mC << 8) + cloc];            // E+ table
          float r2 = re * tw.x - iv * tw.y, i2 = iv * tw.x + re * tw.y;
          outp[(size_t)((s_idx << 8) + mC) * 256 + cloc] = packbf(r2, i2);
        } else {                                        // MODE 4: final y
          const float sc = 1.0f / 65536.0f;
          float* y0 = yout + ((size_t)s_idx << 16) + (mC << 8) + cloc;
          y0[0] = re * sc;        // y[2s][c+256r]
          y0[32768] = iv * sc;    // y[2s+1][c+256r]
        }
      }
    }
  }
}

extern "C" void kernel_launch(void* const* d_in, const int* in_sizes, int n_in,
                              void* d_out, int out_size, void* d_ws, size_t ws_size,
                              hipStream_t stream) {
  const float* x = (const float*)d_in[0];     // [256][32768] fp32
  const float* filt = (const float*)d_in[1];  // [1][32768] fp32
  float* Y = (float*)d_out;                   // [256][32768] fp32

  char* ws = (char*)d_ws;
  unsigned short* A1 = (unsigned short*)(ws + 0);              // 256 KB
  unsigned short* A2 = (unsigned short*)(ws + 0x40000);        // 512 KB
  unsigned short* A3 = (unsigned short*)(ws + 0xC0000);        // 512 KB
  unsigned short* A4 = (unsigned short*)(ws + 0x140000);       // 256 KB
  float2* Gw  = (float2*)(ws + 0x180000);                      // 512 KB
  float2* WtT = (float2*)(ws + 0x200000);                      // 512 KB
  float2* Tw  = (float2*)(ws + 0x280000);                      // 512 KB
  unsigned short* Zp = (unsigned short*)(ws + (3u << 20));     // 16 MB  [3,19)
  unsigned short* G2 = (unsigned short*)(ws + 19922944u);      // 32 MB  [19,51)
  unsigned short* P  = (unsigned short*)(ws + 53477376u);      // 32 MB  [51,83)
  unsigned short* H2 = (unsigned short*)(ws + (3u << 20));     // 32 MB, reuses Zp+G2 (dead)

  hipLaunchKernelGGL(prep_all, dim3(4608), dim3(256), 0, stream,
                     x, filt, A1, A2, A3, A4, (uint32_t*)Zp, Gw, Tw);
  hipLaunchKernelGGL(prep_wb, dim3(256), dim3(256), 0, stream, Gw, WtT);

  hipLaunchKernelGGL((dft_stage<1, 8>), dim3(1024), dim3(256), 0, stream,
                     A1, Zp, (uint32_t*)G2, (float*)nullptr, Tw);
  hipLaunchKernelGGL((dft_stage<2, 16>), dim3(1024), dim3(256), 0, stream,
                     A2, G2, (uint32_t*)P, (float*)nullptr, WtT);
  hipLaunchKernelGGL((dft_stage<3, 16>), dim3(1024), dim3(256), 0, stream,
                     A3, P, (uint32_t*)H2, (float*)nullptr, Tw);
  hipLaunchKernelGGL((dft_stage<4, 16>), dim3(512), dim3(256), 0, stream,
                     A4, H2, (uint32_t*)nullptr, Y, Tw);
}

// Round 3
// 189.496 us; speedup vs baseline: 1.0866x; 1.0546x over previous
//
#include <hip/hip_runtime.h>
#include <cstdint>

typedef __attribute__((ext_vector_type(8))) short short8;
typedef __attribute__((ext_vector_type(4))) float floatx4;

#define TWO_PI 6.283185307179586f

__device__ __forceinline__ unsigned short f2bf(float f) {
  union { float f; uint32_t u; } c; c.f = f;
  uint32_t u = c.u;
  u += 0x7FFFu + ((u >> 16) & 1u);   // RNE
  return (unsigned short)(u >> 16);
}
__device__ __forceinline__ uint32_t packbf(float re, float im) {
  return (uint32_t)f2bf(re) | ((uint32_t)f2bf(im) << 16);
}

// ---------------------------------------------------------------------------
// Four-step DFT convolution, N = 65536 = 256 x 256, t = c + 256 r, k = k1 + 256 k2.
// z_s = x[2s] + i x[2s+1].  All 256-pt DFT stages are real bf16 MFMA GEMMs via
// the 2x2 rotation embedding.
// ---------------------------------------------------------------------------

// Merged prep: blocks [0,3072) build A1..A4; [3072,4096) transpose/pack x->Zp;
// [4096,4352) compute Gw[k1][c] (root-table inner loop); [4352,4608) Tw[k1][c].
__global__ __launch_bounds__(256) void prep_all(
    const float* __restrict__ x, const float* __restrict__ filt,
    unsigned short* __restrict__ A1, unsigned short* __restrict__ A2,
    unsigned short* __restrict__ A3, unsigned short* __restrict__ A4,
    uint32_t* __restrict__ Zp, float2* __restrict__ Gw,
    float2* __restrict__ Tw) {
  __shared__ float2 roots[256];
  const int bid = blockIdx.x;
  const int tid = threadIdx.x;
  const float w256 = TWO_PI / 256.0f;
  if (bid < 3072) {
    int idx = bid * 256 + tid;
    if (idx < 131072) {                       // A1 [512x256], E-(k1 r/256)
      int col = idx & 255, row = idx >> 8;
      int k1 = row >> 1, d = row & 1, r = col >> 1, e = col & 1;
      float th = (float)((k1 * r) & 255) * w256;
      float sn, cs; __sincosf(th, &sn, &cs);
      A1[idx] = f2bf(d == 0 ? (e == 0 ? cs : sn) : (e == 0 ? -sn : cs));
    } else if (idx < 393216) {                // A2 [512x512], E-(k2 c/256)
      int j = idx - 131072;
      int col = j & 511, row = j >> 9;
      int k2 = row >> 1, d = row & 1, cc = col >> 1, e = col & 1;
      float th = (float)((k2 * cc) & 255) * w256;
      float sn, cs; __sincosf(th, &sn, &cs);
      A2[j] = f2bf(d == 0 ? (e == 0 ? cs : sn) : (e == 0 ? -sn : cs));
    } else if (idx < 655360) {                // A3 [512x512], rows 2c+d, E+(k2 c/256)
      int j = idx - 393216;
      int col = j & 511, row = j >> 9;
      int cc = row >> 1, d = row & 1, k2 = col >> 1, e = col & 1;
      float th = (float)((k2 * cc) & 255) * w256;
      float sn, cs; __sincosf(th, &sn, &cs);
      A3[j] = f2bf(d == 0 ? (e == 0 ? cs : -sn) : (e == 0 ? sn : cs));
    } else {                                  // A4 [256x512], rows 2r+d, E+(k1 r/256)
      int j = idx - 655360;
      int col = j & 511, row = j >> 9;
      int r = row >> 1, d = row & 1, k1 = col >> 1, e = col & 1;
      float th = (float)((k1 * r) & 255) * w256;
      float sn, cs; __sincosf(th, &sn, &cs);
      A4[j] = f2bf(d == 0 ? (e == 0 ? cs : -sn) : (e == 0 ? sn : cs));
    }
  } else if (bid < 4096) {                    // Zp[(s*256+c)][r] packed bf16 pair
    int b2 = bid - 3072;                      // 1024 blocks: (s, r-chunk of 16)
    int s = b2 >> 3, rq = b2 & 7;
    const float* x0 = x + (size_t)(2 * s) * 32768;
    const float* x1 = x0 + 32768;
    uint32_t v[16];
    #pragma unroll
    for (int rr = 0; rr < 16; ++rr) {
      int t = tid + 256 * (rq * 16 + rr);
      v[rr] = (uint32_t)f2bf(x0[t]) | ((uint32_t)f2bf(x1[t]) << 16);
    }
    uint32_t* dst = Zp + (size_t)(s * 256 + tid) * 128 + rq * 16;
    #pragma unroll
    for (int j = 0; j < 16; j += 4)
      *(uint4*)(dst + j) = make_uint4(v[j], v[j + 1], v[j + 2], v[j + 3]);
  } else if (bid < 4352) {                    // Gw[k1][c], fp32, root-table loop
    int k1 = bid - 4096, c = tid;
    { float sn, cs; __sincosf((float)tid * w256, &sn, &cs);
      roots[tid] = make_float2(cs, sn); }     // identical values to __sincosf(j*w256)
    __syncthreads();
    float ar = 0.f, ai = 0.f;
    for (int r = 0; r < 128; ++r) {
      float v = filt[c + 256 * r];
      float2 wv = roots[(k1 * r) & 255];      // wave-uniform -> LDS broadcast
      ar += v * wv.x; ai -= v * wv.y;
    }
    float th = (float)((k1 * c) & 65535) * (TWO_PI / 65536.0f);
    float sn, cs; __sincosf(th, &sn, &cs);
    Gw[(k1 << 8) + c] = make_float2(ar * cs + ai * sn, ai * cs - ar * sn);
  } else {                                    // Tw[k1][c] = (cos, sin) of k1*c/65536
    int k1 = bid - 4352, c = tid;
    float th = (float)((k1 * c) & 65535) * (TWO_PI / 65536.0f);
    float sn, cs; __sincosf(th, &sn, &cs);
    Tw[(k1 << 8) + c] = make_float2(cs, sn);
  }
}

// WtT[k2][k1] = sum_c Gw[k1][c] E-(k2 c/256)   (fp32, TRANSPOSED for coalesced
// epilogue).  Root-table inner loop: no sincos in the 256-iter chain.
__global__ __launch_bounds__(256) void prep_wb(const float2* __restrict__ Gw,
                                               float2* __restrict__ WtT) {
  __shared__ float2 roots[256];
  int k1 = blockIdx.x, k2 = threadIdx.x;
  { float sn, cs; __sincosf((float)k2 * (TWO_PI / 256.0f), &sn, &cs);
    roots[k2] = make_float2(cs, sn); }
  __syncthreads();
  float ar = 0.f, ai = 0.f;
  for (int c = 0; c < 256; ++c) {
    float2 g = Gw[(k1 << 8) + c];             // wave-uniform broadcast
    float2 wv = roots[(k2 * c) & 255];        // LDS gather
    ar += g.x * wv.x + g.y * wv.y;
    ai += g.y * wv.x - g.x * wv.y;
  }
  WtT[(k2 << 8) + k1] = make_float2(ar, ai);
}

// One DFT stage = real bf16 GEMM C[m][n] = sum_k A[m][k] B[n][k] + mode epilogue.
// Double-buffered LDS staging, one barrier per K-iter.  (R0-verbatim loop.)
// MODE 1: *Tw(E-) -> G2[(s,k1)][c].   MODE 2: *WtT -> P[(s,k1)][k2] (LDS transpose).
// MODE 3: *Tw(E+) -> H2[(s,c)][k1].   MODE 4: write y (scale 1/65536).
template <int MODE, int KITERS>
__global__ __launch_bounds__(256, 2) void dft_stage(
    const unsigned short* __restrict__ Af,
    const unsigned short* __restrict__ Bd,
    uint32_t* __restrict__ outp,
    float* __restrict__ yout,
    const float2* __restrict__ tab) {
  __shared__ unsigned short Sm[32768];        // As0|As1|Bs0|Bs1, 16 KB each
  constexpr int KP = KITERS * 64;

  const int mt = blockIdx.x >> 8;
  const int nt = blockIdx.x & 255;
  const int m0 = mt * 128, n0 = nt * 128;

  const int tid = threadIdx.x;
  const int w = tid >> 6, lane = tid & 63;
  const int qlo = lane & 15, qhi = lane >> 4;
  const int wr = w >> 1, wc = w & 1;
  const int r8 = lane >> 3, pl = lane & 7, sj = pl ^ r8, q3 = qlo & 7;

  floatx4 acc[4][4];
  #pragma unroll
  for (int i = 0; i < 4; ++i)
    #pragma unroll
    for (int j = 0; j < 4; ++j) acc[i][j] = (floatx4){0.f, 0.f, 0.f, 0.f};

  auto issue = [&](int it, int buf) {
    const int k0 = it * 64;
    unsigned short* Asb = Sm + buf * 8192;
    unsigned short* Bsb = Sm + 16384 + buf * 8192;
    #pragma unroll
    for (int q = 0; q < 4; ++q) {
      const int R = w * 32 + q * 8 + r8;
      const unsigned short* gA = Af + (size_t)(m0 + R) * KP + k0 + sj * 8;
      const unsigned short* gB = Bd + (size_t)(n0 + R) * KP + k0 + sj * 8;
      __builtin_amdgcn_global_load_lds(
          (const __attribute__((address_space(1))) uint32_t*)gA,
          (__attribute__((address_space(3))) uint32_t*)&Asb[(w * 32 + q * 8) * 64], 16, 0, 0);
      __builtin_amdgcn_global_load_lds(
          (const __attribute__((address_space(1))) uint32_t*)gB,
          (__attribute__((address_space(3))) uint32_t*)&Bsb[(w * 32 + q * 8) * 64], 16, 0, 0);
    }
  };

  issue(0, 0);
  for (int it = 0; it < KITERS; ++it) {
    __syncthreads();                          // drains prev iter's prefetch (vmcnt)
    if (it + 1 < KITERS) issue(it + 1, (it + 1) & 1);
    const unsigned short* Ab = Sm + (it & 1) * 8192;
    const unsigned short* Bb = Sm + 16384 + (it & 1) * 8192;
    #pragma unroll
    for (int ks = 0; ks < 2; ++ks) {
      short8 a[4], bb[4];
      #pragma unroll
      for (int im = 0; im < 4; ++im) {
        const int R = wr * 64 + im * 16 + qlo;
        a[im] = *(const short8*)&Ab[R * 64 + (((ks * 4 + qhi) ^ q3) << 3)];
      }
      #pragma unroll
      for (int in = 0; in < 4; ++in) {
        const int R = wc * 64 + in * 16 + qlo;
        bb[in] = *(const short8*)&Bb[R * 64 + (((ks * 4 + qhi) ^ q3) << 3)];
      }
      #pragma unroll
      for (int im = 0; im < 4; ++im)
        #pragma unroll
        for (int in = 0; in < 4; ++in)
          acc[im][in] = __builtin_amdgcn_mfma_f32_16x16x32_bf16(a[im], bb[in], acc[im][in], 0, 0, 0);
    }
  }

  const int s_idx = n0 >> 8;                  // block-constant (128 | 256)
  const int cl0 = n0 & 255;

  if (MODE == 2) {
    __syncthreads();                          // staging buffers now dead -> reuse
    uint32_t* Tr = (uint32_t*)Sm;             // [128 n][68 pad] u32
    #pragma unroll
    for (int im = 0; im < 4; ++im) {
      const int mloc = wr * 32 + im * 8 + qhi * 2;
      #pragma unroll
      for (int in = 0; in < 4; ++in) {
        const int nloc = wc * 64 + in * 16 + qlo;
        #pragma unroll
        for (int pp = 0; pp < 2; ++pp) {
          const int mC = (m0 >> 1) + mloc + pp;         // global k2
          float re = acc[im][in][2 * pp], iv = acc[im][in][2 * pp + 1];
          float2 wv = tab[(mC << 8) + cl0 + nloc];      // WtT, coalesced (lanes->k1)
          float r2 = re * wv.x - iv * wv.y, i2 = re * wv.y + iv * wv.x;
          Tr[nloc * 68 + mloc + pp] = packbf(r2, i2);
        }
      }
    }
    __syncthreads();
    const int ln = tid >> 1, half = tid & 1;
    uint32_t* dst = outp + (size_t)((s_idx << 8) + cl0 + ln) * 256 + (m0 >> 1) + half * 32;
    const uint32_t* srcp = Tr + ln * 68 + half * 32;
    #pragma unroll
    for (int j = 0; j < 32; j += 4)
      *(uint4*)(dst + j) = *(const uint4*)(srcp + j);
    return;
  }

  #pragma unroll
  for (int im = 0; im < 4; ++im) {
    const int mloc = wr * 32 + im * 8 + qhi * 2;
    #pragma unroll
    for (int in = 0; in < 4; ++in) {
      const int nloc = wc * 64 + in * 16 + qlo;
      const int cloc = cl0 + nloc;
      #pragma unroll
      for (int pp = 0; pp < 2; ++pp) {
        const int mC = (m0 >> 1) + mloc + pp;
        float re = acc[im][in][2 * pp], iv = acc[im][in][2 * pp + 1];
        if (MODE == 1) {
          float2 tw = tab[(mC << 8) + cloc];            // E- table (coalesced)
          float r2 = re * tw.x + iv * tw.y, i2 = iv * tw.x - re * tw.y;
          outp[(size_t)((s_idx << 8) + mC) * 256 + cloc] = packbf(r2, i2);
        } else if (MODE == 3) {
          float2 tw = tab[(mC << 8) + cloc];            // E+ table
          float r2 = re * tw.x - iv * tw.y, i2 = iv * tw.x + re * tw.y;
          outp[(size_t)((s_idx << 8) + mC) * 256 + cloc] = packbf(r2, i2);
        } else {                                        // MODE 4: final y
          const float sc = 1.0f / 65536.0f;
          float* y0 = yout + ((size_t)s_idx << 16) + (mC << 8) + cloc;
          y0[0] = re * sc;        // y[2s][c+256r]
          y0[32768] = iv * sc;    // y[2s+1][c+256r]
        }
      }
    }
  }
}

extern "C" void kernel_launch(void* const* d_in, const int* in_sizes, int n_in,
                              void* d_out, int out_size, void* d_ws, size_t ws_size,
                              hipStream_t stream) {
  const float* x = (const float*)d_in[0];     // [256][32768] fp32
  const float* filt = (const float*)d_in[1];  // [1][32768] fp32
  float* Y = (float*)d_out;                   // [256][32768] fp32

  char* ws = (char*)d_ws;
  unsigned short* A1 = (unsigned short*)(ws + 0);              // 256 KB
  unsigned short* A2 = (unsigned short*)(ws + 0x40000);        // 512 KB
  unsigned short* A3 = (unsigned short*)(ws + 0xC0000);        // 512 KB
  unsigned short* A4 = (unsigned short*)(ws + 0x140000);       // 256 KB
  float2* Gw  = (float2*)(ws + 0x180000);                      // 512 KB
  float2* WtT = (float2*)(ws + 0x200000);                      // 512 KB
  float2* Tw  = (float2*)(ws + 0x280000);                      // 512 KB
  unsigned short* Zp = (unsigned short*)(ws + (3u << 20));     // 16 MB  [3,19)
  unsigned short* G2 = (unsigned short*)(ws + 19922944u);      // 32 MB  [19,51)
  unsigned short* P  = (unsigned short*)(ws + 53477376u);      // 32 MB  [51,83)
  unsigned short* H2 = (unsigned short*)(ws + (3u << 20));     // 32 MB, reuses Zp+G2 (dead)

  hipLaunchKernelGGL(prep_all, dim3(4608), dim3(256), 0, stream,
                     x, filt, A1, A2, A3, A4, (uint32_t*)Zp, Gw, Tw);
  hipLaunchKernelGGL(prep_wb, dim3(256), dim3(256), 0, stream, Gw, WtT);

  hipLaunchKernelGGL((dft_stage<1, 4>), dim3(1024), dim3(256), 0, stream,
                     A1, Zp, (uint32_t*)G2, (float*)nullptr, Tw);
  hipLaunchKernelGGL((dft_stage<2, 8>), dim3(1024), dim3(256), 0, stream,
                     A2, G2, (uint32_t*)P, (float*)nullptr, WtT);
  hipLaunchKernelGGL((dft_stage<3, 8>), dim3(1024), dim3(256), 0, stream,
                     A3, P, (uint32_t*)H2, (float*)nullptr, Tw);
  hipLaunchKernelGGL((dft_stage<4, 8>), dim3(512), dim3(256), 0, stream,
                     A4, H2, (uint32_t*)nullptr, Y, Tw);
}